// Round 11
// baseline (109.248 us; speedup 1.0000x reference)
//
#include <hip/hip_runtime.h>
#include <hip/hip_fp16.h>

// MCLoss: mean |lap(gt) - lap(pr)| == mean |lap(gt - pr)|  (laplacian linear).
// B=16, N=100000, M=9, nb[:,0]==i.
//
// Round-11 = round-10 + NONTEMPORAL gather loads (L1 bypass experiment).
// Ledger: 7 k2 designs (payload 32/64/128B, Q=1/2/4, 8-24 waves/CU,
// L2-resident or not) all land 102-113us; only payload-halving ever won
// (r6, -8.5us). => k2 is bound by per-CU miss concurrency (~12-15 fills,
// ~24cy/request effective), NOT bandwidth/MLP. Table is 6.4MB vs 32KB L1
// (hit ~0.5%): L1 contributes nothing but its MSHRs may cap concurrency.
// nt loads on the 16 row-gathers stream past L1; if the cap is L1-MSHR,
// k2 drops; if neutral, the cap is deeper (TCP queue) -> structural floor.
//
//   t8 [(N+1) rows x 64B]: fp8 e4m3 (x,y,z,pad) x 16 batches. Neighbors AND
//     centers decode from it (quant bias ~4.5e-4 << 1.35e-2). Row N zeroed.
//   nbp [N rows x 32B]: nb[:,1:9] repacked -> 4 x uint4 prologue loads.
// k2: 4 lanes share an i-pair; lane = batch-quad; 18 gathers in flight.
// k1: TI=64 (6 blocks/CU), f32x4 LDS stores (+4 pad), fp8 pack, nbp repack.
// NOTE: cooperative launch fails silently under graph capture (r5 lesson).

#define NT 256
#define TI 64   // i's per k1 tile

typedef float f32x4 __attribute__((ext_vector_type(4)));
typedef float f32x2 __attribute__((ext_vector_type(2)));
typedef unsigned int u32x4 __attribute__((ext_vector_type(4)));

__global__ __launch_bounds__(NT) void k1_diff_pack(
    const float* __restrict__ gt, const float* __restrict__ pr,
    uint4* __restrict__ t8, int* __restrict__ nbp,
    const int* __restrict__ nb, float* __restrict__ out, int N) {
  __shared__ __align__(16) float sm[16][3 * TI + 4];  // stride 196; 12.5 KB
  const int chunk = blockIdx.x;
  const int i0 = chunk * TI;
  const int ni = min(TI, N - i0);
  const int nf = 3 * ni;
  const int tid = threadIdx.x;

  // Phase 1: 16 slabs x 3*TI consecutive floats, vec4 nontemporal loads,
  // vec4 LDS stores. (b*N + i0)*3 = b*300000 + 192*chunk -> 16B aligned
  // (N%4==0 guarded at launch).
#pragma unroll
  for (int k = 0; k < (16 * 3 * TI) / (4 * NT); k++) {   // 3 iters
    int f4 = tid + k * NT;
    int bs = f4 / (3 * TI / 4);          // /48
    int o4 = f4 - bs * (3 * TI / 4);
    int off = o4 * 4;
    size_t gbase = ((size_t)bs * N + i0) * 3;
    if (off + 4 <= nf) {
      f32x4 gv = __builtin_nontemporal_load((const f32x4*)(gt + gbase + off));
      f32x4 pv = __builtin_nontemporal_load((const f32x4*)(pr + gbase + off));
      *(f32x4*)&sm[bs][off] = gv - pv;
    } else {
#pragma unroll
      for (int c = 0; c < 4; c++) {
        int o = off + c;
        float v = 0.0f;
        if (o < nf) v = gt[gbase + o] - pr[gbase + o];
        sm[bs][o] = v;
      }
    }
  }
  __syncthreads();

  // Phase 2: fp8 rows, (i, bquad) -> uint4 (batches 4bq..4bq+3, 4B each).
  {
    int el = tid;                        // TI*4 = 256 == NT: single step
    int il = el >> 2;
    int bq = el & 3;
    if (il < ni) {
      unsigned int w[4];
#pragma unroll
      for (int c = 0; c < 4; c++) {
        int b = bq * 4 + c;
        float x = sm[b][il * 3 + 0];
        float y = sm[b][il * 3 + 1];
        float z = sm[b][il * 3 + 2];
        int uu = __builtin_amdgcn_cvt_pk_fp8_f32(x, y, 0, false);
        uu = __builtin_amdgcn_cvt_pk_fp8_f32(z, 0.0f, uu, true);
        w[c] = (unsigned int)uu;
      }
      uint4 o; o.x = w[0]; o.y = w[1]; o.z = w[2]; o.w = w[3];
      t8[(size_t)(i0 + il) * 4 + bq] = o;
    }
  }

  // Phase 3: repack nb[:,1:9] into aligned 32B rows (8 ints).
#pragma unroll
  for (int k = 0; k < (TI * 8) / NT; k++) {              // 2 iters
    int el = tid + k * NT;
    int il = el >> 3;
    int j = el & 7;
    if (il < ni)
      nbp[(size_t)(i0 + il) * 8 + j] = nb[(size_t)(i0 + il) * 9 + 1 + j];
  }

  if (chunk == 0) {
    if (tid < 4) {   // zero fp8 row N (absorbs idx==N)
      uint4 z; z.x = z.y = z.z = z.w = 0u;
      t8[(size_t)N * 4 + tid] = z;
    }
    if (tid == 8) *out = 0.0f;
  }
}

__device__ __forceinline__ void fp8_sub(unsigned int u, float& ax, float& ay,
                                        float& az) {
  f32x2 xy = __builtin_amdgcn_cvt_pk_f32_fp8((int)u, false);
  f32x2 zp = __builtin_amdgcn_cvt_pk_f32_fp8((int)u, true);
  ax -= xy.x; ay -= xy.y; az -= zp.x;
}

__device__ __forceinline__ void fp8_center(unsigned int u, float w, float& ax,
                                           float& ay, float& az) {
  f32x2 xy = __builtin_amdgcn_cvt_pk_f32_fp8((int)u, false);
  f32x2 zp = __builtin_amdgcn_cvt_pk_f32_fp8((int)u, true);
  ax = xy.x * w; ay = xy.y * w; az = zp.x * w;
}

__global__ __launch_bounds__(NT) void k2_lap_loss(
    const u32x4* __restrict__ t8, const uint4* __restrict__ nbp,
    const float* __restrict__ nn, float* __restrict__ out, int N,
    float scale) {
  const int f = blockIdx.x * NT + threadIdx.x;
  const int u = f >> 2;          // i-pair; 4 lanes share it
  const int bq = f & 3;          // batch quad (batches 4bq..4bq+3)
  const bool val = (u < (N >> 1));   // N even on fast path
  const int i0 = val ? 2 * u : 0;
  const int i1 = i0 + 1;

  // --- issue ALL independent loads up front ---
  uint4 nA0 = nbp[(size_t)i0 * 2];     // neighbors 0..3 of i0
  uint4 nA1 = nbp[(size_t)i0 * 2 + 1]; // neighbors 4..7 of i0
  uint4 nB0 = nbp[(size_t)i1 * 2];
  uint4 nB1 = nbp[(size_t)i1 * 2 + 1];
  float w0 = nn[i0], w1 = nn[i1];
  u32x4 cA = t8[(size_t)i0 * 4 + bq];  // centers: sequential, keep cached
  u32x4 cB = t8[(size_t)i1 * 4 + bq];
  int ia[8] = {(int)nA0.x, (int)nA0.y, (int)nA0.z, (int)nA0.w,
               (int)nA1.x, (int)nA1.y, (int)nA1.z, (int)nA1.w};
  int ib[8] = {(int)nB0.x, (int)nB0.y, (int)nB0.z, (int)nB0.w,
               (int)nB1.x, (int)nB1.y, (int)nB1.z, (int)nB1.w};
  // Random row-gathers: NONTEMPORAL (bypass 32KB L1 whose hit rate is ~0.5%;
  // frees its MSHR tracking if that is the concurrency cap).
  u32x4 vA[8], vB[8];
#pragma unroll
  for (int j = 0; j < 8; j++)
    vA[j] = __builtin_nontemporal_load(&t8[(size_t)ia[j] * 4 + bq]);
#pragma unroll
  for (int j = 0; j < 8; j++)
    vB[j] = __builtin_nontemporal_load(&t8[(size_t)ib[j] * 4 + bq]);

  float s = 0.0f;
  {
    float ax[4], ay[4], az[4];
    fp8_center(cA.x, w0, ax[0], ay[0], az[0]);
    fp8_center(cA.y, w0, ax[1], ay[1], az[1]);
    fp8_center(cA.z, w0, ax[2], ay[2], az[2]);
    fp8_center(cA.w, w0, ax[3], ay[3], az[3]);
#pragma unroll
    for (int j = 0; j < 8; j++) {
      fp8_sub(vA[j].x, ax[0], ay[0], az[0]);
      fp8_sub(vA[j].y, ax[1], ay[1], az[1]);
      fp8_sub(vA[j].z, ax[2], ay[2], az[2]);
      fp8_sub(vA[j].w, ax[3], ay[3], az[3]);
    }
#pragma unroll
    for (int c = 0; c < 4; c++)
      s += fabsf(ax[c]) + fabsf(ay[c]) + fabsf(az[c]);
  }
  {
    float ax[4], ay[4], az[4];
    fp8_center(cB.x, w1, ax[0], ay[0], az[0]);
    fp8_center(cB.y, w1, ax[1], ay[1], az[1]);
    fp8_center(cB.z, w1, ax[2], ay[2], az[2]);
    fp8_center(cB.w, w1, ax[3], ay[3], az[3]);
#pragma unroll
    for (int j = 0; j < 8; j++) {
      fp8_sub(vB[j].x, ax[0], ay[0], az[0]);
      fp8_sub(vB[j].y, ax[1], ay[1], az[1]);
      fp8_sub(vB[j].z, ax[2], ay[2], az[2]);
      fp8_sub(vB[j].w, ax[3], ay[3], az[3]);
    }
#pragma unroll
    for (int c = 0; c < 4; c++)
      s += fabsf(ax[c]) + fabsf(ay[c]) + fabsf(az[c]);
  }
  s = val ? s : 0.0f;

  // wave (64-lane) reduction, then block, then one pre-scaled atomic
#pragma unroll
  for (int off = 32; off > 0; off >>= 1) s += __shfl_down(s, off);
  __shared__ float smr[NT / 64];
  int lane = threadIdx.x & 63, wv = threadIdx.x >> 6;
  if (lane == 0) smr[wv] = s;
  __syncthreads();
  if (threadIdx.x == 0) {
    float tt = 0.0f;
#pragma unroll
    for (int k = 0; k < NT / 64; k++) tt += smr[k];
    atomicAdd(out, tt * scale);
  }
}

// ---------- fallback path (tiny ws / K != 8 / B != 16): direct fp32 ----------
__global__ void k0_zero(float* __restrict__ out) {
  if (threadIdx.x == 0) *out = 0.0f;
}

__global__ __launch_bounds__(NT) void k2_direct(
    const float* __restrict__ gt, const float* __restrict__ pr,
    const int* __restrict__ nb, const float* __restrict__ nn,
    float* __restrict__ out, int N, int K, int B, float scale) {
  int u = blockIdx.x * NT + threadIdx.x;
  float s = 0.0f;
  if (u < B * N) {
    int b = u / N;
    int i = u - b * N;
    size_t cidx = ((size_t)b * N + i) * 3;
    float w = nn[i];
    float ax = (gt[cidx] - pr[cidx]) * w;
    float ay = (gt[cidx + 1] - pr[cidx + 1]) * w;
    float az = (gt[cidx + 2] - pr[cidx + 2]) * w;
    const int* row = nb + (size_t)i * (K + 1) + 1;
    for (int j = 0; j < K; j++) {
      int idx = row[j];
      if (idx < N) {
        size_t p = ((size_t)b * N + idx) * 3;
        ax -= (gt[p] - pr[p]);
        ay -= (gt[p + 1] - pr[p + 1]);
        az -= (gt[p + 2] - pr[p + 2]);
      }
    }
    s = fabsf(ax) + fabsf(ay) + fabsf(az);
  }
#pragma unroll
  for (int off = 32; off > 0; off >>= 1) s += __shfl_down(s, off);
  __shared__ float smr[NT / 64];
  int lane = threadIdx.x & 63, wv = threadIdx.x >> 6;
  if (lane == 0) smr[wv] = s;
  __syncthreads();
  if (threadIdx.x == 0) {
    float tt = 0.0f;
#pragma unroll
    for (int k = 0; k < NT / 64; k++) tt += smr[k];
    atomicAdd(out, tt * scale);
  }
}

extern "C" void kernel_launch(void* const* d_in, const int* in_sizes, int n_in,
                              void* d_out, int out_size, void* d_ws, size_t ws_size,
                              hipStream_t stream) {
  const float* gt = (const float*)d_in[0];
  const float* pr = (const float*)d_in[1];
  const int*   nb = (const int*)d_in[2];
  const float* nn = (const float*)d_in[3];
  int N = in_sizes[3];               // 100000
  int M = in_sizes[2] / N;           // 9
  int K = M - 1;                     // 8
  int B = in_sizes[0] / (3 * N);     // 16

  float scale = 1.0f / ((float)B * (float)N * 3.0f);
  size_t t8_bytes = (size_t)(N + 1) * 64;
  size_t nbp_off = (t8_bytes + 63) & ~(size_t)63;
  size_t need = nbp_off + (size_t)N * 32;

  if (K == 8 && B == 16 && (N % 4) == 0 && N >= 2 && ws_size >= need) {
    uint4* t8 = (uint4*)d_ws;
    int* nbp = (int*)((char*)d_ws + nbp_off);

    int b1 = (N + TI - 1) / TI;
    k1_diff_pack<<<b1, NT, 0, stream>>>(gt, pr, t8, nbp, nb, (float*)d_out, N);

    int units = (N / 2) * 4;           // threads (4 lanes per i-pair)
    int b2 = (units + NT - 1) / NT;
    k2_lap_loss<<<b2, NT, 0, stream>>>((const u32x4*)t8, (const uint4*)nbp,
                                       nn, (float*)d_out, N, scale);
  } else {
    k0_zero<<<1, 64, 0, stream>>>((float*)d_out);
    int b2 = (B * N + NT - 1) / NT;
    k2_direct<<<b2, NT, 0, stream>>>(gt, pr, nb, nn, (float*)d_out, N, K, B,
                                     scale);
  }
}

// Round 12
// 105.456 us; speedup vs baseline: 1.0360x; 1.0360x over previous
//
#include <hip/hip_runtime.h>
#include <hip/hip_fp16.h>

// MCLoss: mean |lap(gt) - lap(pr)| == mean |lap(gt - pr)|  (laplacian linear).
// B=16, N=100000, M=9, nb[:,0]==i.
//
// FINAL (round-12) = round-10/round-8 best (102.7-103.7us), r11's
// nontemporal gathers reverted (they cost +5.5us: cap is not L1-MSHR).
//
// Design ledger (8 k2 variants): service time ~9.5ns per random 64B
// line-request per CU, INVARIANT across payload (32/64/128B), L2 residency,
// occupancy (8-24 waves/CU), per-thread MLP (9-36), and L1 policy. Only
// request-count reduction ever won (r6: 1.6M->800K sectors, -8.5us).
// 800K = N*K neighbor-visits x one 64B minimum-granule request, fully
// consumed = algorithmic minimum. k2 is at its floor (~30us).
// Budget: fill 45 (harness poison) + k1 ~9 (stream floor) + k2 ~30 +
// gaps ~15 (fusion blocked: coop launch fails under graph capture (r5);
// software barrier unsafe, ws is poison-filled) => ~100us structural floor.
//
//   t8 [(N+1) rows x 64B]: fp8 e4m3 (x,y,z,pad) x 16 batches. Neighbors AND
//     centers decode from it (quant bias ~4.5e-4 << 1.35e-2). Row N zeroed
//     (absorbs idx==N).
//   nbp [N rows x 32B]: nb[:,1:9] repacked -> 4 x uint4 prologue loads.
// k2: 4 lanes share an i-pair; lane = batch-quad (16B of each 64B row);
//     18 independent gathers in flight per thread.
// k1: TI=64 (6 blocks/CU), f32x4 LDS stores (+4 pad), fp8 pack, nbp repack.

#define NT 256
#define TI 64   // i's per k1 tile

typedef float f32x4 __attribute__((ext_vector_type(4)));
typedef float f32x2 __attribute__((ext_vector_type(2)));

__global__ __launch_bounds__(NT) void k1_diff_pack(
    const float* __restrict__ gt, const float* __restrict__ pr,
    uint4* __restrict__ t8, int* __restrict__ nbp,
    const int* __restrict__ nb, float* __restrict__ out, int N) {
  __shared__ __align__(16) float sm[16][3 * TI + 4];  // stride 196; 12.5 KB
  const int chunk = blockIdx.x;
  const int i0 = chunk * TI;
  const int ni = min(TI, N - i0);
  const int nf = 3 * ni;
  const int tid = threadIdx.x;

  // Phase 1: 16 slabs x 3*TI consecutive floats, vec4 nontemporal loads,
  // vec4 LDS stores. (b*N + i0)*3 = b*300000 + 192*chunk -> 16B aligned
  // (N%4==0 guarded at launch).
#pragma unroll
  for (int k = 0; k < (16 * 3 * TI) / (4 * NT); k++) {   // 3 iters
    int f4 = tid + k * NT;
    int bs = f4 / (3 * TI / 4);          // /48
    int o4 = f4 - bs * (3 * TI / 4);
    int off = o4 * 4;
    size_t gbase = ((size_t)bs * N + i0) * 3;
    if (off + 4 <= nf) {
      f32x4 gv = __builtin_nontemporal_load((const f32x4*)(gt + gbase + off));
      f32x4 pv = __builtin_nontemporal_load((const f32x4*)(pr + gbase + off));
      *(f32x4*)&sm[bs][off] = gv - pv;
    } else {
#pragma unroll
      for (int c = 0; c < 4; c++) {
        int o = off + c;
        float v = 0.0f;
        if (o < nf) v = gt[gbase + o] - pr[gbase + o];
        sm[bs][o] = v;
      }
    }
  }
  __syncthreads();

  // Phase 2: fp8 rows, (i, bquad) -> uint4 (batches 4bq..4bq+3, 4B each).
  // Bank pattern: il*3 -> 16 distinct banks; disjoint halves for bq parity;
  // 2 lanes/bank = free (m136).
  {
    int el = tid;                        // TI*4 = 256 == NT: single step
    int il = el >> 2;
    int bq = el & 3;
    if (il < ni) {
      unsigned int w[4];
#pragma unroll
      for (int c = 0; c < 4; c++) {
        int b = bq * 4 + c;
        float x = sm[b][il * 3 + 0];
        float y = sm[b][il * 3 + 1];
        float z = sm[b][il * 3 + 2];
        int uu = __builtin_amdgcn_cvt_pk_fp8_f32(x, y, 0, false);
        uu = __builtin_amdgcn_cvt_pk_fp8_f32(z, 0.0f, uu, true);
        w[c] = (unsigned int)uu;
      }
      uint4 o; o.x = w[0]; o.y = w[1]; o.z = w[2]; o.w = w[3];
      t8[(size_t)(i0 + il) * 4 + bq] = o;
    }
  }

  // Phase 3: repack nb[:,1:9] into aligned 32B rows (8 ints).
#pragma unroll
  for (int k = 0; k < (TI * 8) / NT; k++) {              // 2 iters
    int el = tid + k * NT;
    int il = el >> 3;
    int j = el & 7;
    if (il < ni)
      nbp[(size_t)(i0 + il) * 8 + j] = nb[(size_t)(i0 + il) * 9 + 1 + j];
  }

  if (chunk == 0) {
    if (tid < 4) {   // zero fp8 row N (absorbs idx==N)
      uint4 z; z.x = z.y = z.z = z.w = 0u;
      t8[(size_t)N * 4 + tid] = z;
    }
    if (tid == 8) *out = 0.0f;
  }
}

__device__ __forceinline__ void fp8_sub(unsigned int u, float& ax, float& ay,
                                        float& az) {
  f32x2 xy = __builtin_amdgcn_cvt_pk_f32_fp8((int)u, false);
  f32x2 zp = __builtin_amdgcn_cvt_pk_f32_fp8((int)u, true);
  ax -= xy.x; ay -= xy.y; az -= zp.x;
}

__device__ __forceinline__ void fp8_center(unsigned int u, float w, float& ax,
                                           float& ay, float& az) {
  f32x2 xy = __builtin_amdgcn_cvt_pk_f32_fp8((int)u, false);
  f32x2 zp = __builtin_amdgcn_cvt_pk_f32_fp8((int)u, true);
  ax = xy.x * w; ay = xy.y * w; az = zp.x * w;
}

__global__ __launch_bounds__(NT) void k2_lap_loss(
    const uint4* __restrict__ t8, const uint4* __restrict__ nbp,
    const float* __restrict__ nn, float* __restrict__ out, int N,
    float scale) {
  const int f = blockIdx.x * NT + threadIdx.x;
  const int u = f >> 2;          // i-pair; 4 lanes share it
  const int bq = f & 3;          // batch quad (batches 4bq..4bq+3)
  const bool val = (u < (N >> 1));   // N even on fast path
  const int i0 = val ? 2 * u : 0;
  const int i1 = i0 + 1;

  // --- issue ALL independent loads up front ---
  uint4 nA0 = nbp[(size_t)i0 * 2];     // neighbors 0..3 of i0
  uint4 nA1 = nbp[(size_t)i0 * 2 + 1]; // neighbors 4..7 of i0
  uint4 nB0 = nbp[(size_t)i1 * 2];
  uint4 nB1 = nbp[(size_t)i1 * 2 + 1];
  float w0 = nn[i0], w1 = nn[i1];
  uint4 cA = t8[(size_t)i0 * 4 + bq];  // 4 lanes -> full 64B row, coalesced
  uint4 cB = t8[(size_t)i1 * 4 + bq];
  int ia[8] = {(int)nA0.x, (int)nA0.y, (int)nA0.z, (int)nA0.w,
               (int)nA1.x, (int)nA1.y, (int)nA1.z, (int)nA1.w};
  int ib[8] = {(int)nB0.x, (int)nB0.y, (int)nB0.z, (int)nB0.w,
               (int)nB1.x, (int)nB1.y, (int)nB1.z, (int)nB1.w};
  uint4 vA[8], vB[8];
#pragma unroll
  for (int j = 0; j < 8; j++) vA[j] = t8[(size_t)ia[j] * 4 + bq];
#pragma unroll
  for (int j = 0; j < 8; j++) vB[j] = t8[(size_t)ib[j] * 4 + bq];

  float s = 0.0f;
  {
    float ax[4], ay[4], az[4];
    fp8_center(cA.x, w0, ax[0], ay[0], az[0]);
    fp8_center(cA.y, w0, ax[1], ay[1], az[1]);
    fp8_center(cA.z, w0, ax[2], ay[2], az[2]);
    fp8_center(cA.w, w0, ax[3], ay[3], az[3]);
#pragma unroll
    for (int j = 0; j < 8; j++) {
      fp8_sub(vA[j].x, ax[0], ay[0], az[0]);
      fp8_sub(vA[j].y, ax[1], ay[1], az[1]);
      fp8_sub(vA[j].z, ax[2], ay[2], az[2]);
      fp8_sub(vA[j].w, ax[3], ay[3], az[3]);
    }
#pragma unroll
    for (int c = 0; c < 4; c++)
      s += fabsf(ax[c]) + fabsf(ay[c]) + fabsf(az[c]);
  }
  {
    float ax[4], ay[4], az[4];
    fp8_center(cB.x, w1, ax[0], ay[0], az[0]);
    fp8_center(cB.y, w1, ax[1], ay[1], az[1]);
    fp8_center(cB.z, w1, ax[2], ay[2], az[2]);
    fp8_center(cB.w, w1, ax[3], ay[3], az[3]);
#pragma unroll
    for (int j = 0; j < 8; j++) {
      fp8_sub(vB[j].x, ax[0], ay[0], az[0]);
      fp8_sub(vB[j].y, ax[1], ay[1], az[1]);
      fp8_sub(vB[j].z, ax[2], ay[2], az[2]);
      fp8_sub(vB[j].w, ax[3], ay[3], az[3]);
    }
#pragma unroll
    for (int c = 0; c < 4; c++)
      s += fabsf(ax[c]) + fabsf(ay[c]) + fabsf(az[c]);
  }
  s = val ? s : 0.0f;

  // wave (64-lane) reduction, then block, then one pre-scaled atomic
#pragma unroll
  for (int off = 32; off > 0; off >>= 1) s += __shfl_down(s, off);
  __shared__ float smr[NT / 64];
  int lane = threadIdx.x & 63, wv = threadIdx.x >> 6;
  if (lane == 0) smr[wv] = s;
  __syncthreads();
  if (threadIdx.x == 0) {
    float tt = 0.0f;
#pragma unroll
    for (int k = 0; k < NT / 64; k++) tt += smr[k];
    atomicAdd(out, tt * scale);
  }
}

// ---------- fallback path (tiny ws / K != 8 / B != 16): direct fp32 ----------
__global__ void k0_zero(float* __restrict__ out) {
  if (threadIdx.x == 0) *out = 0.0f;
}

__global__ __launch_bounds__(NT) void k2_direct(
    const float* __restrict__ gt, const float* __restrict__ pr,
    const int* __restrict__ nb, const float* __restrict__ nn,
    float* __restrict__ out, int N, int K, int B, float scale) {
  int u = blockIdx.x * NT + threadIdx.x;
  float s = 0.0f;
  if (u < B * N) {
    int b = u / N;
    int i = u - b * N;
    size_t cidx = ((size_t)b * N + i) * 3;
    float w = nn[i];
    float ax = (gt[cidx] - pr[cidx]) * w;
    float ay = (gt[cidx + 1] - pr[cidx + 1]) * w;
    float az = (gt[cidx + 2] - pr[cidx + 2]) * w;
    const int* row = nb + (size_t)i * (K + 1) + 1;
    for (int j = 0; j < K; j++) {
      int idx = row[j];
      if (idx < N) {
        size_t p = ((size_t)b * N + idx) * 3;
        ax -= (gt[p] - pr[p]);
        ay -= (gt[p + 1] - pr[p + 1]);
        az -= (gt[p + 2] - pr[p + 2]);
      }
    }
    s = fabsf(ax) + fabsf(ay) + fabsf(az);
  }
#pragma unroll
  for (int off = 32; off > 0; off >>= 1) s += __shfl_down(s, off);
  __shared__ float smr[NT / 64];
  int lane = threadIdx.x & 63, wv = threadIdx.x >> 6;
  if (lane == 0) smr[wv] = s;
  __syncthreads();
  if (threadIdx.x == 0) {
    float tt = 0.0f;
#pragma unroll
    for (int k = 0; k < NT / 64; k++) tt += smr[k];
    atomicAdd(out, tt * scale);
  }
}

extern "C" void kernel_launch(void* const* d_in, const int* in_sizes, int n_in,
                              void* d_out, int out_size, void* d_ws, size_t ws_size,
                              hipStream_t stream) {
  const float* gt = (const float*)d_in[0];
  const float* pr = (const float*)d_in[1];
  const int*   nb = (const int*)d_in[2];
  const float* nn = (const float*)d_in[3];
  int N = in_sizes[3];               // 100000
  int M = in_sizes[2] / N;           // 9
  int K = M - 1;                     // 8
  int B = in_sizes[0] / (3 * N);     // 16

  float scale = 1.0f / ((float)B * (float)N * 3.0f);
  size_t t8_bytes = (size_t)(N + 1) * 64;
  size_t nbp_off = (t8_bytes + 63) & ~(size_t)63;
  size_t need = nbp_off + (size_t)N * 32;

  if (K == 8 && B == 16 && (N % 4) == 0 && N >= 2 && ws_size >= need) {
    uint4* t8 = (uint4*)d_ws;
    int* nbp = (int*)((char*)d_ws + nbp_off);

    int b1 = (N + TI - 1) / TI;
    k1_diff_pack<<<b1, NT, 0, stream>>>(gt, pr, t8, nbp, nb, (float*)d_out, N);

    int units = (N / 2) * 4;           // threads (4 lanes per i-pair)
    int b2 = (units + NT - 1) / NT;
    k2_lap_loss<<<b2, NT, 0, stream>>>(t8, (const uint4*)nbp, nn,
                                       (float*)d_out, N, scale);
  } else {
    k0_zero<<<1, 64, 0, stream>>>((float*)d_out);
    int b2 = (B * N + NT - 1) / NT;
    k2_direct<<<b2, NT, 0, stream>>>(gt, pr, nb, nn, (float*)d_out, N, K, B,
                                     scale);
  }
}